// Round 7
// baseline (1766.758 us; speedup 1.0000x reference)
//
#include <hip/hip_runtime.h>
#include <math.h>

#define NN 16384      // nodes
#define E1N 65536     // edges level 1
#define NBATCH 256
#define NC2 65536     // clusters (level 2 and level 3)
#define KH 128        // edge-MLP hidden
#define OCSTR 136     // oc stride in LDS M tile (f16)
#define NSTR4 1096    // node stride = 8*136+8 (f16)
#define ETILE 16      // edges per staged tile

typedef _Float16 f16;
typedef _Float16 f16x2 __attribute__((ext_vector_type(2)));
typedef _Float16 f16x4 __attribute__((ext_vector_type(4)));
typedef _Float16 f16x8 __attribute__((ext_vector_type(8)));
typedef float    f32x4 __attribute__((ext_vector_type(4)));

__device__ __forceinline__ float elu1(float x){ return x > 0.f ? x : expm1f(x); }

__device__ __forceinline__ float dot2acc(f16x2 a, f16x2 b, float c){
#if __has_builtin(__builtin_amdgcn_fdot2)
  return __builtin_amdgcn_fdot2(a, b, c, false);
#else
  return fmaf((float)a[0], (float)b[0], fmaf((float)a[1], (float)b[1], c));
#endif
}

// ---------------- generic counting + 3-phase scan ----------------
__global__ __launch_bounds__(256) void k_count(const int* __restrict__ arr, int* __restrict__ cnt, int n){
  int i = blockIdx.x*256 + threadIdx.x;
  if (i < n) atomicAdd(&cnt[arr[i]], 1);
}

__global__ __launch_bounds__(256) void k_scan1(const int* __restrict__ deg,
    int* __restrict__ ptr, int* __restrict__ partials){
  __shared__ int buf[256];
  int i = blockIdx.x*256 + threadIdx.x, t = threadIdx.x;
  int v = deg[i];
  buf[t] = v; __syncthreads();
  for (int o = 1; o < 256; o <<= 1){
    int x = (t >= o) ? buf[t-o] : 0;
    __syncthreads(); buf[t] += x; __syncthreads();
  }
  ptr[i] = buf[t] - v;
  if (t == 255) partials[blockIdx.x] = buf[255];
}

__global__ __launch_bounds__(256) void k_scan2(int* __restrict__ partials, int nb){
  __shared__ int buf[256];
  int t = threadIdx.x;
  int v = (t < nb) ? partials[t] : 0;
  buf[t] = v; __syncthreads();
  for (int o = 1; o < 256; o <<= 1){
    int x = (t >= o) ? buf[t-o] : 0;
    __syncthreads(); buf[t] += x; __syncthreads();
  }
  if (t < nb) partials[t] = buf[t] - v;
}

__global__ __launch_bounds__(256) void k_scan3(const int* __restrict__ partials,
    int* __restrict__ ptr, int* __restrict__ cur){
  int i = blockIdx.x*256 + threadIdx.x;
  int v = ptr[i] + partials[blockIdx.x];
  ptr[i] = v; cur[i] = v;
}

// ---------------- CSR fills ----------------
__global__ __launch_bounds__(256) void k_fill_edge(const int* __restrict__ ei, int* __restrict__ cursor,
    int* __restrict__ eids, int* __restrict__ srcs, int* __restrict__ dsts){
  int e = blockIdx.x*256 + threadIdx.x;
  if (e >= E1N) return;
  int s = ei[e];
  int p = atomicAdd(&cursor[s], 1);
  eids[p] = e; srcs[p] = s; dsts[p] = ei[E1N + e];
}

__global__ __launch_bounds__(256) void k_fill_dst(const int* __restrict__ eiL, int* __restrict__ cur,
    int* __restrict__ dsrc, int EL){
  int e = blockIdx.x*256 + threadIdx.x;
  if (e >= EL) return;
  int d = eiL[EL + e];
  int p = atomicAdd(&cur[d], 1);
  dsrc[p] = eiL[e];
}

__global__ __launch_bounds__(256) void k_fill_assign(const int* __restrict__ an, const int* __restrict__ ac,
    int* __restrict__ cur, int* __restrict__ an_sorted, int A){
  int a = blockIdx.x*256 + threadIdx.x;
  if (a >= A) return;
  int c = ac[a];
  int p = atomicAdd(&cur[c], 1);
  an_sorted[p] = an[a];
}

// ---------------- small converts ----------------
__global__ __launch_bounds__(256) void k_cvt16(const float* __restrict__ v, f16* __restrict__ o, int n){
  int t = blockIdx.x*256 + threadIdx.x;
  if (t < n) o[t] = (f16)v[t];
}

__global__ __launch_bounds__(256) void k_elu_both(float* __restrict__ v, f16* __restrict__ v16, int n){
  int t = blockIdx.x*256 + threadIdx.x;
  if (t < n){ float r = elu1(v[t]); v[t] = r; v16[t] = (f16)r; }
}

__global__ __launch_bounds__(256) void k_elu(float* __restrict__ v, int n){
  int t = blockIdx.x*256 + threadIdx.x;
  if (t < n) v[t] = elu1(v[t]);
}

// ---------------- NNConv pieces ----------------
// pack [root | b2] into B-frag order, N = 2*MO cols
__global__ __launch_bounds__(256) void k_packPrep(const float* __restrict__ root,
    const float* __restrict__ b2, f16* __restrict__ Bp, int mi, int mo, int S, int NB){
  int t = blockIdx.x*256 + threadIdx.x;
  if (t >= NB*S*512) return;
  int j = t & 7, l = (t >> 3) & 63, cs = t >> 9;
  int s = cs % S, c = cs / S;
  int k_in = s*32 + ((l>>4)<<3) + j;
  int n = c*16 + (l & 15);
  float v = 0.f;
  if (k_in < mi) v = (n < mo) ? root[k_in*mo + n] : b2[k_in*mo + (n - mo)];
  Bp[t] = (f16)v;
}

// outb[n,o] = bias[o] + (x@root)[n,o]; bterm[n,o] = (x@b2)[n,o]   via MFMA
template<int MI, int S, int NB, int MO>
__global__ __launch_bounds__(256) void k_prep_mfma(const f16* __restrict__ A,
    const f16* __restrict__ Bp, const float* __restrict__ bias,
    float* __restrict__ outb, float* __restrict__ bterm){
  int l = threadIdx.x & 63, w = threadIdx.x >> 6;
  int r0 = blockIdx.x*64 + w*16;
  const f16* arow = A + (size_t)(r0 + (l & 15))*MI;
  f16x8 a[S];
  #pragma unroll
  for (int s=0;s<S;s++){
    int koff = s*32 + ((l>>4)<<3);
    if (koff < MI) a[s] = *(const f16x8*)(arow + koff);
    else           a[s] = (f16x8){0,0,0,0,0,0,0,0};
  }
  #pragma unroll
  for (int c=0;c<NB;c++){
    f32x4 acc = (f32x4){0.f,0.f,0.f,0.f};
    #pragma unroll
    for (int s=0;s<S;s++){
      f16x8 b = *(const f16x8*)(Bp + ((size_t)(c*S + s)*64 + l)*8);
      acc = __builtin_amdgcn_mfma_f32_16x16x32_f16(a[s], b, acc, 0, 0, 0);
    }
    int col = c*16 + (l & 15);
    #pragma unroll
    for (int r=0;r<4;r++){
      int row = r0 + ((l>>4)<<2) + r;
      if (col < MO) outb[(size_t)row*MO + col] = acc[r] + bias[col];
      else          bterm[(size_t)row*MO + (col - MO)] = acc[r];
    }
  }
}

// pack FULL W2 into B-frag order; q -> (oc=q>>3, kt=q&7), col k = kt*16 + (l&15)
__global__ __launch_bounds__(256) void k_w2pack_full(const float* __restrict__ W2,
    f16* __restrict__ Bp, int mi, int mo, int S){
  int t = blockIdx.x*256 + threadIdx.x;
  if (t >= mo*8*S*512) return;
  int j = t & 7, l = (t >> 3) & 63, cs = t >> 9;
  int s = cs % S, q = cs / S;
  int oc = q >> 3;
  int k  = (q & 7)*16 + (l & 15);
  int i  = s*32 + ((l>>4)<<3) + j;
  float v = (i < mi) ? W2[(size_t)k*mi*mo + (size_t)i*mo + oc] : 0.f;
  Bp[t] = (f16)v;
}

// FUSED NNConv v2: one WAVE per 4 CSR-consecutive nodes. Barrier-free.
// Per 16-edge tile: stage ea rows -> compute hrelu in LDS (fused edge-MLP);
// per oc-chunk of 8: MFMA M[4n][8oc][128k] -> LDS; consume edges (lane = eslot,oc).
template<int MI, int S, int MO>
__global__ __launch_bounds__(64) void k_nnconv_fused2(const f16* __restrict__ xin16,
    const f16* __restrict__ W2p,
    const int* __restrict__ rowptr, const int* __restrict__ rowend,
    const int* __restrict__ srcs, const int* __restrict__ dsts,
    const int* __restrict__ eids,
    const float* __restrict__ ea, const float* __restrict__ W1,
    const float* __restrict__ b1,
    const float* __restrict__ bterm, float* __restrict__ outb){
  __shared__ __align__(16) f16  M[4*NSTR4];      // 8768 B
  __shared__ __align__(16) f16  hb[ETILE*OCSTR]; // 4352 B
  __shared__ __align__(16) float eas[ETILE*8];   //  512 B
  int l = threadIdx.x;
  int n0 = blockIdx.x*4;
  int estart = rowptr[n0], eend = rowend[n0+3];
  if (estart >= eend) return;                    // wave-uniform
  // A-frags for 4 nodes (clamp rows 4..15 to node 3 to avoid OOB; never read)
  int an = n0 + (((l&15) < 4) ? (l&15) : 3);
  const f16* arow = xin16 + (size_t)an*MI;
  f16x8 a[S];
  #pragma unroll
  for (int s=0;s<S;s++){
    int koff = s*32 + ((l>>4)<<3);
    if (koff < MI) a[s] = *(const f16x8*)(arow + koff);
    else           a[s] = (f16x8){0,0,0,0,0,0,0,0};
  }
  const int NCHUNK = MO/8;
  int eslot = l >> 3, oc = l & 7;
  for (int ebase = estart; ebase < eend; ebase += ETILE){
    int ecnt = eend - ebase; if (ecnt > ETILE) ecnt = ETILE;
    // ---- stage ea rows (7 floats + pad) ----
    for (int idx = l; idx < ecnt*8; idx += 64){
      int e_ = idx >> 3, i = idx & 7;
      eas[idx] = (i < 7) ? ea[(size_t)eids[ebase + e_]*7 + i] : 0.f;
    }
    __asm__ volatile("s_waitcnt vmcnt(0) lgkmcnt(0)" ::: "memory");
    // ---- fused edge-MLP: lane (e = l&15, kg = l>>4) computes 32 k values ----
    {
      int e_ = l & 15, kg = l >> 4;
      if (e_ < ecnt){
        float xr[7];
        #pragma unroll
        for (int i=0;i<7;i++) xr[i] = eas[e_*8 + i];
        #pragma unroll 2
        for (int jj = 0; jj < 32; jj += 4){
          int k0 = kg*32 + jj;
          float4 acc4 = *(const float4*)(b1 + k0);
          #pragma unroll
          for (int i=0;i<7;i++){
            float4 wv = *(const float4*)(W1 + i*KH + k0);
            acc4.x = fmaf(xr[i], wv.x, acc4.x);
            acc4.y = fmaf(xr[i], wv.y, acc4.y);
            acc4.z = fmaf(xr[i], wv.z, acc4.z);
            acc4.w = fmaf(xr[i], wv.w, acc4.w);
          }
          f16x4 hv = { (f16)fmaxf(acc4.x,0.f), (f16)fmaxf(acc4.y,0.f),
                       (f16)fmaxf(acc4.z,0.f), (f16)fmaxf(acc4.w,0.f) };
          *(f16x4*)&hb[e_*OCSTR + k0] = hv;
        }
      }
    }
    __asm__ volatile("s_waitcnt vmcnt(0) lgkmcnt(0)" ::: "memory");
    // ---- chunk loop ----
    for (int c = 0; c < NCHUNK; c++){
      // stage 1: 64 q-tiles via MFMA -> M (lanes 0..15 write rows 0..3)
      #pragma unroll 8
      for (int t = 0; t < 64; t++){
        int q = c*64 + t;
        f32x4 acc = (f32x4){0.f,0.f,0.f,0.f};
        #pragma unroll
        for (int s=0;s<S;s++){
          f16x8 b = *(const f16x8*)(W2p + ((size_t)(q*S + s)*64 + l)*8);
          acc = __builtin_amdgcn_mfma_f32_16x16x32_f16(a[s], b, acc, 0, 0, 0);
        }
        if ((l >> 4) == 0){
          int ocl = t >> 3, kpos = (t & 7)*16 + (l & 15);
          f16* mp = &M[ocl*OCSTR + kpos];
          #pragma unroll
          for (int r=0;r<4;r++)
            mp[(size_t)r*NSTR4] = (f16)acc[r];
        }
      }
      __asm__ volatile("s_waitcnt lgkmcnt(0)" ::: "memory");
      // stage 2: consume edges, 2 rounds of (8 eslots x 8 oc)
      #pragma unroll
      for (int r2 = 0; r2 < 2; r2++){
        int ee = r2*8 + eslot;
        if (ee < ecnt){
          int e = ebase + ee;
          int s_ = srcs[e];
          int ln = s_ - n0;
          float acc = bterm[(size_t)s_*MO + c*8 + oc];
          const f16* mrow = &M[(size_t)ln*NSTR4 + oc*OCSTR];
          const f16* hrow = &hb[ee*OCSTR];
          #pragma unroll 4
          for (int kk=0; kk<16; kk++){
            f16x8 m8 = *(const f16x8*)(mrow + kk*8);
            f16x8 h8 = *(const f16x8*)(hrow + kk*8);
            #pragma unroll
            for (int j=0;j<4;j++){
              f16x2 hp = {h8[2*j], h8[2*j+1]};
              f16x2 mp2 = {m8[2*j], m8[2*j+1]};
              acc = dot2acc(hp, mp2, acc);
            }
          }
          atomicAdd(&outb[(size_t)dsts[e]*MO + c*8 + oc], acc);
        }
      }
      __asm__ volatile("s_waitcnt lgkmcnt(0)" ::: "memory");
    }
  }
}

// ---------------- pooling via cluster-CSR ----------------
__global__ __launch_bounds__(256) void k_pool_gather(const int* __restrict__ aptr,
    const int* __restrict__ aend, const int* __restrict__ an_sorted,
    const float* __restrict__ h, const float* __restrict__ iso,
    f16* __restrict__ h16){
  int l = threadIdx.x & 63, w = threadIdx.x >> 6;
  int c = blockIdx.x*4 + w;
  int st = aptr[c], en = aend[c];
  float acc = 0.f;
  int e = st;
  for (; e+1 < en; e += 2){
    int n0 = an_sorted[e], n1 = an_sorted[e+1];
    acc += h[(size_t)n0*64 + l];
    acc += h[(size_t)n1*64 + l];
  }
  if (e < en) acc += h[(size_t)an_sorted[e]*64 + l];
  int cnt = en - st;
  float val = (cnt > 0) ? acc / (float)cnt : 0.f;
  h16[(size_t)c*128 + l] = (f16)val;
  h16[(size_t)c*128 + 64 + l] = (f16)iso[(size_t)c*64 + l];
}

// ---------------- GraphConv ----------------
__global__ __launch_bounds__(256) void k_packB_gc(const float* __restrict__ Wrel,
    const float* __restrict__ Wroot, f16* __restrict__ Bp, int S){
  int t = blockIdx.x*256 + threadIdx.x;
  if (t >= 8*S*512) return;
  int j = t & 7, l = (t >> 3) & 63, cs = t >> 9;
  int s = cs % S, c = cs / S;
  int k = s*32 + ((l>>4)<<3) + j;
  int n = (c<<4) + (l & 15);
  float v = (n < 64) ? Wrel[k*64 + n] : Wroot[k*64 + (n - 64)];
  Bp[t] = (f16)v;
}

template<int S>
__global__ __launch_bounds__(256) void k_gc_mfma(const f16* __restrict__ A,
    const f16* __restrict__ Bp, const float* __restrict__ bias,
    float* __restrict__ y, float* __restrict__ rbuf){
  int l = threadIdx.x & 63, w = threadIdx.x >> 6;
  int r0 = blockIdx.x*64 + w*16;
  const f16* arow = A + (size_t)(r0 + (l & 15))*(S*32);
  f16x8 a[S];
  #pragma unroll
  for (int s=0;s<S;s++) a[s] = *(const f16x8*)(arow + s*32 + ((l>>4)<<3));
  f32x4 acc[8];
  #pragma unroll
  for (int c=0;c<8;c++) acc[c] = (f32x4){0.f,0.f,0.f,0.f};
  #pragma unroll
  for (int c=0;c<8;c++){
    #pragma unroll
    for (int s=0;s<S;s++){
      f16x8 b = *(const f16x8*)(Bp + ((size_t)(c*S + s)*64 + l)*8);
      acc[c] = __builtin_amdgcn_mfma_f32_16x16x32_f16(a[s], b, acc[c], 0, 0, 0);
    }
  }
  #pragma unroll
  for (int c=0;c<8;c++){
    int col = c*16 + (l & 15);
    #pragma unroll
    for (int r=0;r<4;r++){
      int row = r0 + ((l>>4)<<2) + r;
      if (col < 64) y[(size_t)row*64 + col] = acc[c][r];
      else          rbuf[(size_t)row*64 + (col-64)] = acc[c][r] + bias[col-64];
    }
  }
}

template<bool F16OUT>
__global__ __launch_bounds__(256) void k_gc_gather(const int* __restrict__ dptr,
    const int* __restrict__ dend, const int* __restrict__ dsrc,
    const float* __restrict__ y, const float* __restrict__ rbuf,
    f16* __restrict__ o16, float* __restrict__ o32){
  int l = threadIdx.x & 63, w = threadIdx.x >> 6;
  int n = blockIdx.x*4 + w;
  int st = dptr[n], en = dend[n];
  float acc = rbuf[(size_t)n*64 + l];
  int e = st;
  for (; e+1 < en; e += 2){
    int s0 = dsrc[e], s1 = dsrc[e+1];
    acc += y[(size_t)s0*64 + l];
    acc += y[(size_t)s1*64 + l];
  }
  if (e < en) acc += y[(size_t)dsrc[e]*64 + l];
  float r = elu1(acc);
  if (F16OUT) o16[(size_t)n*64 + l] = (f16)r;
  else        o32[(size_t)n*64 + l] = r;
}

// ---------------- sorted-segment batch sum ----------------
__device__ __forceinline__ int lowerb(const int* __restrict__ a, int n, int key){
  int lo = 0, hi = n;
  while (lo < hi){ int m = (lo + hi) >> 1; if (a[m] < key) lo = m + 1; else hi = m; }
  return lo;
}

__global__ __launch_bounds__(256) void k_batchsum_seg(const int* __restrict__ batch,
    const float* __restrict__ h, float* __restrict__ x123, int n_nodes, int off){
  __shared__ float red[4][64];
  int b = blockIdx.x;
  int lo = lowerb(batch, n_nodes, b);
  int hi = lowerb(batch, n_nodes, b+1);
  int col = threadIdx.x & 63, wq = threadIdx.x >> 6;
  float acc = 0.f;
  for (int n = lo + wq; n < hi; n += 4) acc += h[(size_t)n*64 + col];
  red[wq][col] = acc;
  __syncthreads();
  if (threadIdx.x < 64){
    float s = red[0][threadIdx.x] + red[1][threadIdx.x] + red[2][threadIdx.x] + red[3][threadIdx.x];
    x123[b*192 + off + threadIdx.x] = s;
  }
}

// ---------------- FC head ----------------
__global__ __launch_bounds__(256) void k_fc1(const float* __restrict__ x123,
    const float* __restrict__ W, const float* __restrict__ b, float* __restrict__ t1){
  int t = blockIdx.x*256 + threadIdx.x;
  if (t >= NBATCH*64) return;
  int bb = t >> 6, o = t & 63;
  const float* xr = x123 + bb*192;
  float acc = b[o];
  for (int j=0;j<192;j++) acc = fmaf(xr[j], W[j*64+o] + W[(192+j)*64+o], acc);
  t1[t] = elu1(acc);
}

__global__ __launch_bounds__(256) void k_fc2(const float* __restrict__ t1,
    const float* __restrict__ W, const float* __restrict__ b, float* __restrict__ t2){
  int t = blockIdx.x*256 + threadIdx.x;
  if (t >= NBATCH*32) return;
  int bb = t >> 5, o = t & 31;
  float acc = b[o];
  for (int j=0;j<64;j++) acc = fmaf(t1[bb*64+j], W[j*32+o], acc);
  t2[t] = elu1(acc);
}

__global__ __launch_bounds__(256) void k_fc3(const float* __restrict__ t2,
    const float* __restrict__ W, const float* __restrict__ b, float* __restrict__ out){
  int t = blockIdx.x*256 + threadIdx.x;
  if (t >= NBATCH) return;
  float acc = b[0];
  for (int j=0;j<32;j++) acc = fmaf(t2[t*32+j], W[j], acc);
  out[t] = acc;
}

static inline int cdiv(long long a, int b){ return (int)((a + b - 1) / b); }

extern "C" void kernel_launch(void* const* d_in, const int* in_sizes, int n_in,
                              void* d_out, int out_size, void* d_ws, size_t ws_size,
                              hipStream_t stream) {
  const float* x0    = (const float*)d_in[0];
  const int*   ei    = (const int*)d_in[1];
  const float* ea    = (const float*)d_in[2];
  const int*   batch = (const int*)d_in[3];
  const int*   a2n   = (const int*)d_in[4];
  const int*   a2c   = (const int*)d_in[5];
  const float* iso2  = (const float*)d_in[6];
  const int*   ei2   = (const int*)d_in[7];
  const int*   b2arr = (const int*)d_in[8];
  const int*   a3n   = (const int*)d_in[9];
  const int*   a3c   = (const int*)d_in[10];
  const float* iso3  = (const float*)d_in[11];
  const int*   ei3   = (const int*)d_in[12];
  const int*   b3arr = (const int*)d_in[13];
  const float* nnp[3][6];
  for (int c=0;c<3;c++) for (int p=0;p<6;p++) nnp[c][p] = (const float*)d_in[14 + 6*c + p];
  const float* c4W[3]; const float* c5W[3]; const float* c6W[3]; const float* c7W[3];
  for (int p=0;p<3;p++){ c4W[p]=(const float*)d_in[32+p]; c5W[p]=(const float*)d_in[35+p];
                         c6W[p]=(const float*)d_in[38+p]; c7W[p]=(const float*)d_in[41+p]; }
  const float* fc1W=(const float*)d_in[44]; const float* fc1b=(const float*)d_in[45];
  const float* fc2W=(const float*)d_in[46]; const float* fc2b=(const float*)d_in[47];
  const float* fc3W=(const float*)d_in[48]; const float* fc3b=(const float*)d_in[49];
  float* outp = (float*)d_out;

  // ---- workspace carve ----
  char* ws = (char*)d_ws; size_t off = 0;
  auto alloc = [&](size_t bytes)->void*{ void* p = ws + off; off += (bytes + 255) & ~(size_t)255; return p; };
  const size_t SZ_R0 = (size_t)92*1024*1024;
  char* r0 = (char*)alloc(SZ_R0);
  // phase-1 view (NNConv): W2p 1MB | prepB 16KB | bterm 4MB
  f16*   W2p   = (f16*)r0;
  f16*   prepB = (f16*)(r0 + 2*1024*1024);
  float* bterm = (float*)(r0 + 2*1024*1024 + 64*1024);
  // phase-2 view (levels)
  size_t o2 = 0;
  auto a2 = [&](size_t bytes)->char*{ char* p = r0 + o2; o2 += (bytes + 255) & ~(size_t)255; return p; };
  f16*   h16   = (f16*)  a2((size_t)NC2*128*2);   // 16 MB
  float* ybuf  = (float*)a2((size_t)NC2*64*4);    // 16 MB
  float* rbuf  = (float*)a2((size_t)NC2*64*4);    // 16 MB
  float* gB    = (float*)a2((size_t)NC2*64*4);    // 16 MB
  f16*   g16   = (f16*)  a2((size_t)NC2*64*2);    //  8 MB
  f16*   BpGc  = (f16*)  a2((size_t)8*4*512*2);   // 32 KB
  int*   aptr  = (int*)  a2((size_t)NC2*4);
  int*   acur  = (int*)  a2((size_t)NC2*4);
  int*   dptr  = (int*)  a2((size_t)NC2*4);
  int*   dcur  = (int*)  a2((size_t)NC2*4);
  int*   ldeg  = (int*)  a2((size_t)NC2*4);
  int*   ans   = (int*)  a2((size_t)196608*4);
  int*   dsrc  = (int*)  a2((size_t)262144*4);
  // note: phase-2 region must not clobber phase-1's bterm before NNConvs end;
  // phase-2 buffers are only written after all NNConvs complete.
  // persistent
  float* hA    = (float*)alloc((size_t)NN*32*4);
  float* hB    = (float*)alloc((size_t)NN*64*4);
  float* hC    = (float*)alloc((size_t)NN*64*4);
  f16*   x016  = (f16*)  alloc((size_t)NN*16*2);
  f16*   hA16  = (f16*)  alloc((size_t)NN*32*2);
  f16*   hB16  = (f16*)  alloc((size_t)NN*64*2);
  int*   deg   = (int*)  alloc((size_t)NN*4);
  int*   cursor= (int*)  alloc((size_t)NN*4);
  int*   rowptr= (int*)  alloc((size_t)NN*4);
  int*   eids  = (int*)  alloc((size_t)E1N*4);
  int*   srcs  = (int*)  alloc((size_t)E1N*4);
  int*   dsts  = (int*)  alloc((size_t)E1N*4);
  int*   parts = (int*)  alloc((size_t)256*4);
  float* x123  = (float*)alloc((size_t)NBATCH*192*4);
  float* t1    = (float*)alloc((size_t)NBATCH*64*4);
  float* t2    = (float*)alloc((size_t)NBATCH*32*4);
  (void)ws_size; (void)n_in; (void)in_sizes; (void)out_size;

  auto scan = [&](const int* dg, int n, int* ptr, int* cur){
    k_scan1<<<n/256,256,0,stream>>>(dg, ptr, parts);
    k_scan2<<<1,256,0,stream>>>(parts, n/256);
    k_scan3<<<n/256,256,0,stream>>>(parts, ptr, cur);
  };

  // ---- edge CSR by src (once; reused by all 3 convs) ----
  hipMemsetAsync(deg, 0, (size_t)NN*4, stream);
  k_count<<<cdiv(E1N,256),256,0,stream>>>(ei, deg, E1N);
  scan(deg, NN, rowptr, cursor);
  k_fill_edge<<<cdiv(E1N,256),256,0,stream>>>(ei, cursor, eids, srcs, dsts);
  k_cvt16<<<cdiv((long long)NN*16,256),256,0,stream>>>(x0, x016, NN*16);

  // ---- NNConv x3 (fused, wave-autonomous) ----
  auto run_nnconv = [&](const f16* xin16, int mi, int mo,
                        const float* const* P, float* outb, f16* out16){
    const float* W1=P[0]; const float* b1=P[1]; const float* W2=P[2];
    const float* b2=P[3]; const float* root=P[4]; const float* bias=P[5];
    const int S = (mi > 32) ? 2 : 1;
    const int NB = (2*mo)/16;
    k_packPrep<<<cdiv((long long)NB*S*512,256),256,0,stream>>>(root, b2, prepB, mi, mo, S, NB);
    if (mi==16)      k_prep_mfma<16,1,4,32><<<NN/64,256,0,stream>>>(xin16, prepB, bias, outb, bterm);
    else if (mi==32) k_prep_mfma<32,1,8,64><<<NN/64,256,0,stream>>>(xin16, prepB, bias, outb, bterm);
    else             k_prep_mfma<64,2,8,64><<<NN/64,256,0,stream>>>(xin16, prepB, bias, outb, bterm);
    k_w2pack_full<<<cdiv((long long)mo*8*S*512,256),256,0,stream>>>(W2, W2p, mi, mo, S);
    if (mi==16)      k_nnconv_fused2<16,1,32><<<NN/4,64,0,stream>>>(xin16, W2p, rowptr, cursor, srcs, dsts, eids, ea, W1, b1, bterm, outb);
    else if (mi==32) k_nnconv_fused2<32,1,64><<<NN/4,64,0,stream>>>(xin16, W2p, rowptr, cursor, srcs, dsts, eids, ea, W1, b1, bterm, outb);
    else             k_nnconv_fused2<64,2,64><<<NN/4,64,0,stream>>>(xin16, W2p, rowptr, cursor, srcs, dsts, eids, ea, W1, b1, bterm, outb);
    if (out16) k_elu_both<<<cdiv((long long)NN*mo,256),256,0,stream>>>(outb, out16, NN*mo);
    else       k_elu<<<cdiv((long long)NN*mo,256),256,0,stream>>>(outb, NN*mo);
  };
  run_nnconv(x016, 16, 32, nnp[0], hA, hA16);
  run_nnconv(hA16, 32, 64, nnp[1], hB, hB16);
  run_nnconv(hB16, 64, 64, nnp[2], hC, nullptr);

  // level-1 batch sum
  k_batchsum_seg<<<NBATCH,256,0,stream>>>(batch, hC, x123, NN, 0);

  // ---- levels 2 and 3 ----
  auto run_level = [&](const int* an, const int* ac, int A, const float* iso,
                       const int* eiL, int EL, const int* batchL,
                       const float* const* cA, const float* const* cB, int off123){
    hipMemsetAsync(ldeg, 0, (size_t)NC2*4, stream);
    k_count<<<cdiv(A,256),256,0,stream>>>(ac, ldeg, A);
    scan(ldeg, NC2, aptr, acur);
    k_fill_assign<<<cdiv(A,256),256,0,stream>>>(an, ac, acur, ans, A);
    hipMemsetAsync(ldeg, 0, (size_t)NC2*4, stream);
    k_count<<<cdiv(EL,256),256,0,stream>>>(eiL + EL, ldeg, EL);
    scan(ldeg, NC2, dptr, dcur);
    k_fill_dst<<<cdiv(EL,256),256,0,stream>>>(eiL, dcur, dsrc, EL);
    k_pool_gather<<<NC2/4,256,0,stream>>>(aptr, acur, ans, hC, iso, h16);
    k_packB_gc<<<cdiv((long long)8*4*512,256),256,0,stream>>>(cA[0], cA[1], BpGc, 4);
    k_gc_mfma<4><<<NC2/64,256,0,stream>>>(h16, BpGc, cA[2], ybuf, rbuf);
    k_gc_gather<true><<<NC2/4,256,0,stream>>>(dptr, dcur, dsrc, ybuf, rbuf, g16, nullptr);
    k_packB_gc<<<cdiv((long long)8*2*512,256),256,0,stream>>>(cB[0], cB[1], BpGc, 2);
    k_gc_mfma<2><<<NC2/64,256,0,stream>>>(g16, BpGc, cB[2], ybuf, rbuf);
    k_gc_gather<false><<<NC2/4,256,0,stream>>>(dptr, dcur, dsrc, ybuf, rbuf, nullptr, gB);
    k_batchsum_seg<<<NBATCH,256,0,stream>>>(batchL, gB, x123, NC2, off123);
  };
  run_level(a2n, a2c, 131072, iso2, ei2, 262144, b2arr, c4W, c5W, 64);
  run_level(a3n, a3c, 196608, iso3, ei3, 262144, b3arr, c6W, c7W, 128);

  // ---- FC head ----
  k_fc1<<<cdiv((long long)NBATCH*64,256),256,0,stream>>>(x123, fc1W, fc1b, t1);
  k_fc2<<<cdiv((long long)NBATCH*32,256),256,0,stream>>>(t1, fc2W, fc2b, t2);
  k_fc3<<<cdiv(NBATCH,256),256,0,stream>>>(t2, fc3W, fc3b, outp);
}

// Round 8
// 868.334 us; speedup vs baseline: 2.0347x; 2.0347x over previous
//
#include <hip/hip_runtime.h>
#include <math.h>

#define NN 16384      // nodes
#define E1N 65536     // edges level 1
#define NBATCH 256
#define NC2 65536     // clusters (level 2 and level 3)
#define KH 128        // edge-MLP hidden
#define MNSTR 1092    // M node stride (f16): 1092/2=546 dwords, 546*4 mod 32 = 8 -> conflict-free row groups
#define OCS 136       // oc stride (f16)
#define ECAP 96       // edges per super-tile

typedef _Float16 f16;
typedef _Float16 f16x2 __attribute__((ext_vector_type(2)));
typedef _Float16 f16x4 __attribute__((ext_vector_type(4)));
typedef _Float16 f16x8 __attribute__((ext_vector_type(8)));
typedef float    f32x4 __attribute__((ext_vector_type(4)));

__device__ __forceinline__ float elu1(float x){ return x > 0.f ? x : expm1f(x); }

__device__ __forceinline__ float dot2acc(f16x2 a, f16x2 b, float c){
#if __has_builtin(__builtin_amdgcn_fdot2)
  return __builtin_amdgcn_fdot2(a, b, c, false);
#else
  return fmaf((float)a[0], (float)b[0], fmaf((float)a[1], (float)b[1], c));
#endif
}

// ---------------- generic counting + 3-phase scan ----------------
__global__ __launch_bounds__(256) void k_count(const int* __restrict__ arr, int* __restrict__ cnt, int n){
  int i = blockIdx.x*256 + threadIdx.x;
  if (i < n) atomicAdd(&cnt[arr[i]], 1);
}

__global__ __launch_bounds__(256) void k_scan1(const int* __restrict__ deg,
    int* __restrict__ ptr, int* __restrict__ partials){
  __shared__ int buf[256];
  int i = blockIdx.x*256 + threadIdx.x, t = threadIdx.x;
  int v = deg[i];
  buf[t] = v; __syncthreads();
  for (int o = 1; o < 256; o <<= 1){
    int x = (t >= o) ? buf[t-o] : 0;
    __syncthreads(); buf[t] += x; __syncthreads();
  }
  ptr[i] = buf[t] - v;
  if (t == 255) partials[blockIdx.x] = buf[255];
}

__global__ __launch_bounds__(256) void k_scan2(int* __restrict__ partials, int nb){
  __shared__ int buf[256];
  int t = threadIdx.x;
  int v = (t < nb) ? partials[t] : 0;
  buf[t] = v; __syncthreads();
  for (int o = 1; o < 256; o <<= 1){
    int x = (t >= o) ? buf[t-o] : 0;
    __syncthreads(); buf[t] += x; __syncthreads();
  }
  if (t < nb) partials[t] = buf[t] - v;
}

__global__ __launch_bounds__(256) void k_scan3(const int* __restrict__ partials,
    int* __restrict__ ptr, int* __restrict__ cur){
  int i = blockIdx.x*256 + threadIdx.x;
  int v = ptr[i] + partials[blockIdx.x];
  ptr[i] = v; cur[i] = v;
}

// ---------------- CSR fills ----------------
__global__ __launch_bounds__(256) void k_fill_edge(const int* __restrict__ ei, int* __restrict__ cursor,
    int* __restrict__ eids, int* __restrict__ srcs, int* __restrict__ dsts){
  int e = blockIdx.x*256 + threadIdx.x;
  if (e >= E1N) return;
  int s = ei[e];
  int p = atomicAdd(&cursor[s], 1);
  eids[p] = e; srcs[p] = s; dsts[p] = ei[E1N + e];
}

__global__ __launch_bounds__(256) void k_fill_dst(const int* __restrict__ eiL, int* __restrict__ cur,
    int* __restrict__ dsrc, int EL){
  int e = blockIdx.x*256 + threadIdx.x;
  if (e >= EL) return;
  int d = eiL[EL + e];
  int p = atomicAdd(&cur[d], 1);
  dsrc[p] = eiL[e];
}

__global__ __launch_bounds__(256) void k_fill_assign(const int* __restrict__ an, const int* __restrict__ ac,
    int* __restrict__ cur, int* __restrict__ an_sorted, int A){
  int a = blockIdx.x*256 + threadIdx.x;
  if (a >= A) return;
  int c = ac[a];
  int p = atomicAdd(&cur[c], 1);
  an_sorted[p] = an[a];
}

// ---------------- small converts ----------------
__global__ __launch_bounds__(256) void k_cvt16(const float* __restrict__ v, f16* __restrict__ o, int n){
  int t = blockIdx.x*256 + threadIdx.x;
  if (t < n) o[t] = (f16)v[t];
}

__global__ __launch_bounds__(256) void k_elu_both(float* __restrict__ v, f16* __restrict__ v16, int n){
  int t = blockIdx.x*256 + threadIdx.x;
  if (t < n){ float r = elu1(v[t]); v[t] = r; v16[t] = (f16)r; }
}

__global__ __launch_bounds__(256) void k_elu(float* __restrict__ v, int n){
  int t = blockIdx.x*256 + threadIdx.x;
  if (t < n) v[t] = elu1(v[t]);
}

// ---------------- NNConv pieces ----------------
// pack [root | b2] into B-frag order, N = 2*MO cols
__global__ __launch_bounds__(256) void k_packPrep(const float* __restrict__ root,
    const float* __restrict__ b2, f16* __restrict__ Bp, int mi, int mo, int S, int NB){
  int t = blockIdx.x*256 + threadIdx.x;
  if (t >= NB*S*512) return;
  int j = t & 7, l = (t >> 3) & 63, cs = t >> 9;
  int s = cs % S, c = cs / S;
  int k_in = s*32 + ((l>>4)<<3) + j;
  int n = c*16 + (l & 15);
  float v = 0.f;
  if (k_in < mi) v = (n < mo) ? root[k_in*mo + n] : b2[k_in*mo + (n - mo)];
  Bp[t] = (f16)v;
}

// outb[n,o] = bias[o] + (x@root)[n,o]; bterm[n,o] = (x@b2)[n,o]   via MFMA
template<int MI, int S, int NB, int MO>
__global__ __launch_bounds__(256) void k_prep_mfma(const f16* __restrict__ A,
    const f16* __restrict__ Bp, const float* __restrict__ bias,
    float* __restrict__ outb, float* __restrict__ bterm){
  int l = threadIdx.x & 63, w = threadIdx.x >> 6;
  int r0 = blockIdx.x*64 + w*16;
  const f16* arow = A + (size_t)(r0 + (l & 15))*MI;
  f16x8 a[S];
  #pragma unroll
  for (int s=0;s<S;s++){
    int koff = s*32 + ((l>>4)<<3);
    if (koff < MI) a[s] = *(const f16x8*)(arow + koff);
    else           a[s] = (f16x8){0,0,0,0,0,0,0,0};
  }
  #pragma unroll
  for (int c=0;c<NB;c++){
    f32x4 acc = (f32x4){0.f,0.f,0.f,0.f};
    #pragma unroll
    for (int s=0;s<S;s++){
      f16x8 b = *(const f16x8*)(Bp + ((size_t)(c*S + s)*64 + l)*8);
      acc = __builtin_amdgcn_mfma_f32_16x16x32_f16(a[s], b, acc, 0, 0, 0);
    }
    int col = c*16 + (l & 15);
    #pragma unroll
    for (int r=0;r<4;r++){
      int row = r0 + ((l>>4)<<2) + r;
      if (col < MO) outb[(size_t)row*MO + col] = acc[r] + bias[col];
      else          bterm[(size_t)row*MO + (col - MO)] = acc[r];
    }
  }
}

// pack FULL W2 into B-frag order; q -> (oc=q>>3, kt=q&7), col k = kt*16 + (l&15)
__global__ __launch_bounds__(256) void k_w2pack_full(const float* __restrict__ W2,
    f16* __restrict__ Bp, int mi, int mo, int S){
  int t = blockIdx.x*256 + threadIdx.x;
  if (t >= mo*8*S*512) return;
  int j = t & 7, l = (t >> 3) & 63, cs = t >> 9;
  int s = cs % S, q = cs / S;
  int oc = q >> 3;
  int k  = (q & 7)*16 + (l & 15);
  int i  = s*32 + ((l>>4)<<3) + j;
  float v = (i < mi) ? W2[(size_t)k*mi*mo + (size_t)i*mo + oc] : 0.f;
  Bp[t] = (f16)v;
}

// FUSED NNConv v3: block = 16 CSR-consecutive nodes, 256 threads.
// Super-tiles of <=96 edges: fused edge-MLP -> hb in LDS (once);
// per oc-chunk of 8: MFMA M[16n][8oc][128k] -> LDS; consume edges from LDS only.
template<int MI, int S, int MO>
__global__ __launch_bounds__(256) void k_nnconv_fused3(const f16* __restrict__ xin16,
    const f16* __restrict__ W2p,
    const int* __restrict__ rowptr, const int* __restrict__ rowend,
    const int* __restrict__ srcs, const int* __restrict__ dsts,
    const int* __restrict__ eids,
    const float* __restrict__ ea, const float* __restrict__ W1,
    const float* __restrict__ b1,
    const float* __restrict__ bterm, float* __restrict__ outb){
  __shared__ __align__(16) f16   M[16*MNSTR];    // 34944 B
  __shared__ __align__(16) f16   hb[ECAP*OCS];   // 26112 B
  __shared__ __align__(16) float eas[ECAP*8];    //  3072 B
  int t = threadIdx.x, l = t & 63, w = t >> 6;
  int n0 = blockIdx.x*16;
  int estart = rowptr[n0], eend = rowend[n0+15];
  if (estart >= eend) return;                    // block-uniform
  // A-frags for the 16 nodes (reused across chunks/passes)
  const f16* arow = xin16 + (size_t)(n0 + (l&15))*MI;
  f16x8 a[S];
  #pragma unroll
  for (int s=0;s<S;s++){
    int koff = s*32 + ((l>>4)<<3);
    if (koff < MI) a[s] = *(const f16x8*)(arow + koff);
    else           a[s] = (f16x8){0,0,0,0,0,0,0,0};
  }
  const int NCHUNK = MO/8;
  int oc = t & 7, eslot = t >> 3;                // 32 edge slots
  for (int ebase = estart; ebase < eend; ebase += ECAP){
    int ecnt = eend - ebase; if (ecnt > ECAP) ecnt = ECAP;
    // ---- stage ea rows ----
    for (int idx = t; idx < ecnt*8; idx += 256){
      int e_ = idx >> 3, i = idx & 7;
      eas[idx] = (i < 7) ? ea[(size_t)eids[ebase + e_]*7 + i] : 0.f;
    }
    __syncthreads();
    // ---- fused edge-MLP -> hb (each unit = 4 k values) ----
    for (int idx = t; idx < ecnt*32; idx += 256){
      int e_ = idx >> 5, p = idx & 31;
      int k0 = p*4;
      const float* xr = &eas[e_*8];
      float4 acc4 = *(const float4*)(b1 + k0);
      #pragma unroll
      for (int i=0;i<7;i++){
        float xv = xr[i];
        float4 wv = *(const float4*)(W1 + i*KH + k0);
        acc4.x = fmaf(xv, wv.x, acc4.x);
        acc4.y = fmaf(xv, wv.y, acc4.y);
        acc4.z = fmaf(xv, wv.z, acc4.z);
        acc4.w = fmaf(xv, wv.w, acc4.w);
      }
      f16x4 hv = { (f16)fmaxf(acc4.x,0.f), (f16)fmaxf(acc4.y,0.f),
                   (f16)fmaxf(acc4.z,0.f), (f16)fmaxf(acc4.w,0.f) };
      *(f16x4*)&hb[e_*OCS + k0] = hv;
    }
    __syncthreads();
    // ---- chunk loop ----
    for (int c = 0; c < NCHUNK; c++){
      // stage 1: 64 q-tiles via MFMA -> M
      #pragma unroll
      for (int tt = 0; tt < 16; tt++){
        int q = c*64 + w*16 + tt;
        f32x4 acc = (f32x4){0.f,0.f,0.f,0.f};
        #pragma unroll
        for (int s=0;s<S;s++){
          f16x8 b = *(const f16x8*)(W2p + ((size_t)(q*S + s)*64 + l)*8);
          acc = __builtin_amdgcn_mfma_f32_16x16x32_f16(a[s], b, acc, 0, 0, 0);
        }
        int ocl = w*2 + (tt>>3);
        int kpos = (tt&7)*16 + (l & 15);
        f16* mp = &M[ocl*OCS + kpos];
        #pragma unroll
        for (int r=0;r<4;r++)
          mp[(size_t)(((l>>4)<<2) + r)*MNSTR] = (f16)acc[r];
      }
      __syncthreads();
      // stage 2: consume edges (hb + M from LDS)
      #pragma unroll
      for (int r2 = 0; r2 < ECAP/32; r2++){
        int ee = r2*32 + eslot;
        if (ee < ecnt){
          int e = ebase + ee;
          int s_ = srcs[e];
          int ln = s_ - n0;
          float acc = bterm[(size_t)s_*MO + c*8 + oc];
          const f16* mrow = &M[(size_t)ln*MNSTR + oc*OCS];
          const f16* hrow = &hb[ee*OCS];
          #pragma unroll 4
          for (int kk=0; kk<16; kk++){
            f16x8 h8 = *(const f16x8*)(hrow + kk*8);
            f16x4 m0 = *(const f16x4*)(mrow + kk*8);
            f16x4 m1 = *(const f16x4*)(mrow + kk*8 + 4);
            acc = dot2acc((f16x2){h8[0],h8[1]}, (f16x2){m0[0],m0[1]}, acc);
            acc = dot2acc((f16x2){h8[2],h8[3]}, (f16x2){m0[2],m0[3]}, acc);
            acc = dot2acc((f16x2){h8[4],h8[5]}, (f16x2){m1[0],m1[1]}, acc);
            acc = dot2acc((f16x2){h8[6],h8[7]}, (f16x2){m1[2],m1[3]}, acc);
          }
          atomicAdd(&outb[(size_t)dsts[e]*MO + c*8 + oc], acc);
        }
      }
      __syncthreads();
    }
  }
}

// ---------------- pooling via cluster-CSR ----------------
__global__ __launch_bounds__(256) void k_pool_gather(const int* __restrict__ aptr,
    const int* __restrict__ aend, const int* __restrict__ an_sorted,
    const float* __restrict__ h, const float* __restrict__ iso,
    f16* __restrict__ h16){
  int l = threadIdx.x & 63, w = threadIdx.x >> 6;
  int c = blockIdx.x*4 + w;
  int st = aptr[c], en = aend[c];
  float acc = 0.f;
  int e = st;
  for (; e+1 < en; e += 2){
    int n0 = an_sorted[e], n1 = an_sorted[e+1];
    acc += h[(size_t)n0*64 + l];
    acc += h[(size_t)n1*64 + l];
  }
  if (e < en) acc += h[(size_t)an_sorted[e]*64 + l];
  int cnt = en - st;
  float val = (cnt > 0) ? acc / (float)cnt : 0.f;
  h16[(size_t)c*128 + l] = (f16)val;
  h16[(size_t)c*128 + 64 + l] = (f16)iso[(size_t)c*64 + l];
}

// ---------------- GraphConv ----------------
__global__ __launch_bounds__(256) void k_packB_gc(const float* __restrict__ Wrel,
    const float* __restrict__ Wroot, f16* __restrict__ Bp, int S){
  int t = blockIdx.x*256 + threadIdx.x;
  if (t >= 8*S*512) return;
  int j = t & 7, l = (t >> 3) & 63, cs = t >> 9;
  int s = cs % S, c = cs / S;
  int k = s*32 + ((l>>4)<<3) + j;
  int n = (c<<4) + (l & 15);
  float v = (n < 64) ? Wrel[k*64 + n] : Wroot[k*64 + (n - 64)];
  Bp[t] = (f16)v;
}

template<int S>
__global__ __launch_bounds__(256) void k_gc_mfma(const f16* __restrict__ A,
    const f16* __restrict__ Bp, const float* __restrict__ bias,
    float* __restrict__ y, float* __restrict__ rbuf){
  int l = threadIdx.x & 63, w = threadIdx.x >> 6;
  int r0 = blockIdx.x*64 + w*16;
  const f16* arow = A + (size_t)(r0 + (l & 15))*(S*32);
  f16x8 a[S];
  #pragma unroll
  for (int s=0;s<S;s++) a[s] = *(const f16x8*)(arow + s*32 + ((l>>4)<<3));
  f32x4 acc[8];
  #pragma unroll
  for (int c=0;c<8;c++) acc[c] = (f32x4){0.f,0.f,0.f,0.f};
  #pragma unroll
  for (int c=0;c<8;c++){
    #pragma unroll
    for (int s=0;s<S;s++){
      f16x8 b = *(const f16x8*)(Bp + ((size_t)(c*S + s)*64 + l)*8);
      acc[c] = __builtin_amdgcn_mfma_f32_16x16x32_f16(a[s], b, acc[c], 0, 0, 0);
    }
  }
  #pragma unroll
  for (int c=0;c<8;c++){
    int col = c*16 + (l & 15);
    #pragma unroll
    for (int r=0;r<4;r++){
      int row = r0 + ((l>>4)<<2) + r;
      if (col < 64) y[(size_t)row*64 + col] = acc[c][r];
      else          rbuf[(size_t)row*64 + (col-64)] = acc[c][r] + bias[col-64];
    }
  }
}

template<bool F16OUT>
__global__ __launch_bounds__(256) void k_gc_gather(const int* __restrict__ dptr,
    const int* __restrict__ dend, const int* __restrict__ dsrc,
    const float* __restrict__ y, const float* __restrict__ rbuf,
    f16* __restrict__ o16, float* __restrict__ o32){
  int l = threadIdx.x & 63, w = threadIdx.x >> 6;
  int n = blockIdx.x*4 + w;
  int st = dptr[n], en = dend[n];
  float acc = rbuf[(size_t)n*64 + l];
  int e = st;
  for (; e+1 < en; e += 2){
    int s0 = dsrc[e], s1 = dsrc[e+1];
    acc += y[(size_t)s0*64 + l];
    acc += y[(size_t)s1*64 + l];
  }
  if (e < en) acc += y[(size_t)dsrc[e]*64 + l];
  float r = elu1(acc);
  if (F16OUT) o16[(size_t)n*64 + l] = (f16)r;
  else        o32[(size_t)n*64 + l] = r;
}

// ---------------- sorted-segment batch sum ----------------
__device__ __forceinline__ int lowerb(const int* __restrict__ a, int n, int key){
  int lo = 0, hi = n;
  while (lo < hi){ int m = (lo + hi) >> 1; if (a[m] < key) lo = m + 1; else hi = m; }
  return lo;
}

__global__ __launch_bounds__(256) void k_batchsum_seg(const int* __restrict__ batch,
    const float* __restrict__ h, float* __restrict__ x123, int n_nodes, int off){
  __shared__ float red[4][64];
  int b = blockIdx.x;
  int lo = lowerb(batch, n_nodes, b);
  int hi = lowerb(batch, n_nodes, b+1);
  int col = threadIdx.x & 63, wq = threadIdx.x >> 6;
  float acc = 0.f;
  for (int n = lo + wq; n < hi; n += 4) acc += h[(size_t)n*64 + col];
  red[wq][col] = acc;
  __syncthreads();
  if (threadIdx.x < 64){
    float s = red[0][threadIdx.x] + red[1][threadIdx.x] + red[2][threadIdx.x] + red[3][threadIdx.x];
    x123[b*192 + off + threadIdx.x] = s;
  }
}

// ---------------- FC head ----------------
__global__ __launch_bounds__(256) void k_fc1(const float* __restrict__ x123,
    const float* __restrict__ W, const float* __restrict__ b, float* __restrict__ t1){
  int t = blockIdx.x*256 + threadIdx.x;
  if (t >= NBATCH*64) return;
  int bb = t >> 6, o = t & 63;
  const float* xr = x123 + bb*192;
  float acc = b[o];
  for (int j=0;j<192;j++) acc = fmaf(xr[j], W[j*64+o] + W[(192+j)*64+o], acc);
  t1[t] = elu1(acc);
}

__global__ __launch_bounds__(256) void k_fc2(const float* __restrict__ t1,
    const float* __restrict__ W, const float* __restrict__ b, float* __restrict__ t2){
  int t = blockIdx.x*256 + threadIdx.x;
  if (t >= NBATCH*32) return;
  int bb = t >> 5, o = t & 31;
  float acc = b[o];
  for (int j=0;j<64;j++) acc = fmaf(t1[bb*64+j], W[j*32+o], acc);
  t2[t] = elu1(acc);
}

__global__ __launch_bounds__(256) void k_fc3(const float* __restrict__ t2,
    const float* __restrict__ W, const float* __restrict__ b, float* __restrict__ out){
  int t = blockIdx.x*256 + threadIdx.x;
  if (t >= NBATCH) return;
  float acc = b[0];
  for (int j=0;j<32;j++) acc = fmaf(t2[t*32+j], W[j], acc);
  out[t] = acc;
}

static inline int cdiv(long long a, int b){ return (int)((a + b - 1) / b); }

extern "C" void kernel_launch(void* const* d_in, const int* in_sizes, int n_in,
                              void* d_out, int out_size, void* d_ws, size_t ws_size,
                              hipStream_t stream) {
  const float* x0    = (const float*)d_in[0];
  const int*   ei    = (const int*)d_in[1];
  const float* ea    = (const float*)d_in[2];
  const int*   batch = (const int*)d_in[3];
  const int*   a2n   = (const int*)d_in[4];
  const int*   a2c   = (const int*)d_in[5];
  const float* iso2  = (const float*)d_in[6];
  const int*   ei2   = (const int*)d_in[7];
  const int*   b2arr = (const int*)d_in[8];
  const int*   a3n   = (const int*)d_in[9];
  const int*   a3c   = (const int*)d_in[10];
  const float* iso3  = (const float*)d_in[11];
  const int*   ei3   = (const int*)d_in[12];
  const int*   b3arr = (const int*)d_in[13];
  const float* nnp[3][6];
  for (int c=0;c<3;c++) for (int p=0;p<6;p++) nnp[c][p] = (const float*)d_in[14 + 6*c + p];
  const float* c4W[3]; const float* c5W[3]; const float* c6W[3]; const float* c7W[3];
  for (int p=0;p<3;p++){ c4W[p]=(const float*)d_in[32+p]; c5W[p]=(const float*)d_in[35+p];
                         c6W[p]=(const float*)d_in[38+p]; c7W[p]=(const float*)d_in[41+p]; }
  const float* fc1W=(const float*)d_in[44]; const float* fc1b=(const float*)d_in[45];
  const float* fc2W=(const float*)d_in[46]; const float* fc2b=(const float*)d_in[47];
  const float* fc3W=(const float*)d_in[48]; const float* fc3b=(const float*)d_in[49];
  float* outp = (float*)d_out;

  // ---- workspace carve ----
  char* ws = (char*)d_ws; size_t off = 0;
  auto alloc = [&](size_t bytes)->void*{ void* p = ws + off; off += (bytes + 255) & ~(size_t)255; return p; };
  const size_t SZ_R0 = (size_t)92*1024*1024;
  char* r0 = (char*)alloc(SZ_R0);
  // phase-1 view (NNConv): W2p 1MB | prepB 16KB | bterm 4MB
  f16*   W2p   = (f16*)r0;
  f16*   prepB = (f16*)(r0 + 2*1024*1024);
  float* bterm = (float*)(r0 + 2*1024*1024 + 64*1024);
  // phase-2 view (levels; written only after NNConvs complete)
  size_t o2 = 0;
  auto a2 = [&](size_t bytes)->char*{ char* p = r0 + o2; o2 += (bytes + 255) & ~(size_t)255; return p; };
  f16*   h16   = (f16*)  a2((size_t)NC2*128*2);   // 16 MB
  float* ybuf  = (float*)a2((size_t)NC2*64*4);    // 16 MB
  float* rbuf  = (float*)a2((size_t)NC2*64*4);    // 16 MB
  float* gB    = (float*)a2((size_t)NC2*64*4);    // 16 MB
  f16*   g16   = (f16*)  a2((size_t)NC2*64*2);    //  8 MB
  f16*   BpGc  = (f16*)  a2((size_t)8*4*512*2);   // 32 KB
  int*   aptr  = (int*)  a2((size_t)NC2*4);
  int*   acur  = (int*)  a2((size_t)NC2*4);
  int*   dptr  = (int*)  a2((size_t)NC2*4);
  int*   dcur  = (int*)  a2((size_t)NC2*4);
  int*   ldeg  = (int*)  a2((size_t)NC2*4);
  int*   ans   = (int*)  a2((size_t)196608*4);
  int*   dsrc  = (int*)  a2((size_t)262144*4);
  // persistent
  float* hA    = (float*)alloc((size_t)NN*32*4);
  float* hB    = (float*)alloc((size_t)NN*64*4);
  float* hC    = (float*)alloc((size_t)NN*64*4);
  f16*   x016  = (f16*)  alloc((size_t)NN*16*2);
  f16*   hA16  = (f16*)  alloc((size_t)NN*32*2);
  f16*   hB16  = (f16*)  alloc((size_t)NN*64*2);
  int*   deg   = (int*)  alloc((size_t)NN*4);
  int*   cursor= (int*)  alloc((size_t)NN*4);
  int*   rowptr= (int*)  alloc((size_t)NN*4);
  int*   eids  = (int*)  alloc((size_t)E1N*4);
  int*   srcs  = (int*)  alloc((size_t)E1N*4);
  int*   dsts  = (int*)  alloc((size_t)E1N*4);
  int*   parts = (int*)  alloc((size_t)256*4);
  float* x123  = (float*)alloc((size_t)NBATCH*192*4);
  float* t1    = (float*)alloc((size_t)NBATCH*64*4);
  float* t2    = (float*)alloc((size_t)NBATCH*32*4);
  (void)ws_size; (void)n_in; (void)in_sizes; (void)out_size;

  auto scan = [&](const int* dg, int n, int* ptr, int* cur){
    k_scan1<<<n/256,256,0,stream>>>(dg, ptr, parts);
    k_scan2<<<1,256,0,stream>>>(parts, n/256);
    k_scan3<<<n/256,256,0,stream>>>(parts, ptr, cur);
  };

  // ---- edge CSR by src (once; reused by all 3 convs) ----
  hipMemsetAsync(deg, 0, (size_t)NN*4, stream);
  k_count<<<cdiv(E1N,256),256,0,stream>>>(ei, deg, E1N);
  scan(deg, NN, rowptr, cursor);
  k_fill_edge<<<cdiv(E1N,256),256,0,stream>>>(ei, cursor, eids, srcs, dsts);
  k_cvt16<<<cdiv((long long)NN*16,256),256,0,stream>>>(x0, x016, NN*16);

  // ---- NNConv x3 (fused v3) ----
  auto run_nnconv = [&](const f16* xin16, int mi, int mo,
                        const float* const* P, float* outb, f16* out16){
    const float* W1=P[0]; const float* b1=P[1]; const float* W2=P[2];
    const float* b2=P[3]; const float* root=P[4]; const float* bias=P[5];
    const int S = (mi > 32) ? 2 : 1;
    const int NB = (2*mo)/16;
    k_packPrep<<<cdiv((long long)NB*S*512,256),256,0,stream>>>(root, b2, prepB, mi, mo, S, NB);
    if (mi==16)      k_prep_mfma<16,1,4,32><<<NN/64,256,0,stream>>>(xin16, prepB, bias, outb, bterm);
    else if (mi==32) k_prep_mfma<32,1,8,64><<<NN/64,256,0,stream>>>(xin16, prepB, bias, outb, bterm);
    else             k_prep_mfma<64,2,8,64><<<NN/64,256,0,stream>>>(xin16, prepB, bias, outb, bterm);
    k_w2pack_full<<<cdiv((long long)mo*8*S*512,256),256,0,stream>>>(W2, W2p, mi, mo, S);
    if (mi==16)      k_nnconv_fused3<16,1,32><<<NN/16,256,0,stream>>>(xin16, W2p, rowptr, cursor, srcs, dsts, eids, ea, W1, b1, bterm, outb);
    else if (mi==32) k_nnconv_fused3<32,1,64><<<NN/16,256,0,stream>>>(xin16, W2p, rowptr, cursor, srcs, dsts, eids, ea, W1, b1, bterm, outb);
    else             k_nnconv_fused3<64,2,64><<<NN/16,256,0,stream>>>(xin16, W2p, rowptr, cursor, srcs, dsts, eids, ea, W1, b1, bterm, outb);
    if (out16) k_elu_both<<<cdiv((long long)NN*mo,256),256,0,stream>>>(outb, out16, NN*mo);
    else       k_elu<<<cdiv((long long)NN*mo,256),256,0,stream>>>(outb, NN*mo);
  };
  run_nnconv(x016, 16, 32, nnp[0], hA, hA16);
  run_nnconv(hA16, 32, 64, nnp[1], hB, hB16);
  run_nnconv(hB16, 64, 64, nnp[2], hC, nullptr);

  // level-1 batch sum
  k_batchsum_seg<<<NBATCH,256,0,stream>>>(batch, hC, x123, NN, 0);

  // ---- levels 2 and 3 ----
  auto run_level = [&](const int* an, const int* ac, int A, const float* iso,
                       const int* eiL, int EL, const int* batchL,
                       const float* const* cA, const float* const* cB, int off123){
    hipMemsetAsync(ldeg, 0, (size_t)NC2*4, stream);
    k_count<<<cdiv(A,256),256,0,stream>>>(ac, ldeg, A);
    scan(ldeg, NC2, aptr, acur);
    k_fill_assign<<<cdiv(A,256),256,0,stream>>>(an, ac, acur, ans, A);
    hipMemsetAsync(ldeg, 0, (size_t)NC2*4, stream);
    k_count<<<cdiv(EL,256),256,0,stream>>>(eiL + EL, ldeg, EL);
    scan(ldeg, NC2, dptr, dcur);
    k_fill_dst<<<cdiv(EL,256),256,0,stream>>>(eiL, dcur, dsrc, EL);
    k_pool_gather<<<NC2/4,256,0,stream>>>(aptr, acur, ans, hC, iso, h16);
    k_packB_gc<<<cdiv((long long)8*4*512,256),256,0,stream>>>(cA[0], cA[1], BpGc, 4);
    k_gc_mfma<4><<<NC2/64,256,0,stream>>>(h16, BpGc, cA[2], ybuf, rbuf);
    k_gc_gather<true><<<NC2/4,256,0,stream>>>(dptr, dcur, dsrc, ybuf, rbuf, g16, nullptr);
    k_packB_gc<<<cdiv((long long)8*2*512,256),256,0,stream>>>(cB[0], cB[1], BpGc, 2);
    k_gc_mfma<2><<<NC2/64,256,0,stream>>>(g16, BpGc, cB[2], ybuf, rbuf);
    k_gc_gather<false><<<NC2/4,256,0,stream>>>(dptr, dcur, dsrc, ybuf, rbuf, nullptr, gB);
    k_batchsum_seg<<<NBATCH,256,0,stream>>>(batchL, gB, x123, NC2, off123);
  };
  run_level(a2n, a2c, 131072, iso2, ei2, 262144, b2arr, c4W, c5W, 64);
  run_level(a3n, a3c, 196608, iso3, ei3, 262144, b3arr, c6W, c7W, 128);

  // ---- FC head ----
  k_fc1<<<cdiv((long long)NBATCH*64,256),256,0,stream>>>(x123, fc1W, fc1b, t1);
  k_fc2<<<cdiv((long long)NBATCH*32,256),256,0,stream>>>(t1, fc2W, fc2b, t2);
  k_fc3<<<cdiv(NBATCH,256),256,0,stream>>>(t2, fc3W, fc3b, outp);
}